// Round 4
// baseline (441.254 us; speedup 1.0000x reference)
//
#include <hip/hip_runtime.h>

#define LOG2E 1.4426950408889634f
#define LN2   0.6931471805599453f

typedef __bf16 bf16x2 __attribute__((ext_vector_type(2)));

#define HAVE_BF16_DOT2 __has_builtin(__builtin_amdgcn_fdot2_f32_bf16)

__device__ __forceinline__ float bcastf(float v, int l) {
  return __uint_as_float(__builtin_amdgcn_readlane(__float_as_uint(v), l));
}

// One wave per batch; lane i owns state i. LINEAR-domain recurrence:
//   u'[i] = E[i] * sum_j M[i,j] * u[j] * 2^{-k}
// E = exp(emit) precomputed off the critical path; 2^{-k} is an exact
// power-of-2 rescale with k = exponent of previous step's s[lane0]
// (v_frexp_exp + readfirstlane, lagged one step -> latency hidden).
// exp/log are fully removed from the serial loop. The 64-wide broadcast
// matvec is 32 readlane + 32 v_dot2_f32_bf16 (bf16 pairs packed with one
// DPP quad-perm + one v_perm), halving round-3's 64 rl + 64 fma.
__global__ __launch_bounds__(64, 1) void crf_fwd_33852932227637(
    const float* __restrict__ h,
    const float* __restrict__ trans,
    const int* __restrict__ lengths,
    float* __restrict__ out,
    int T) {
  constexpr int N = 64;
  const int b = blockIdx.x;
  const int lane = threadIdx.x;
  const float* hb = h + (size_t)b * T * N;

#if HAVE_BF16_DOT2
  // M[lane][j] = exp(trans[lane*64+j]) as bf16 pairs (round-to-nearest-ish
  // via +0x8000 before truncation), 32 VGPRs.
  unsigned Mp[32];
  {
    const float4* trow = (const float4*)(trans + lane * N);
#pragma unroll
    for (int q = 0; q < 16; ++q) {
      float4 tq = trow[q];
      unsigned u0 = __float_as_uint(__builtin_amdgcn_exp2f(tq.x * LOG2E)) + 0x8000u;
      unsigned u1 = __float_as_uint(__builtin_amdgcn_exp2f(tq.y * LOG2E)) + 0x8000u;
      unsigned u2 = __float_as_uint(__builtin_amdgcn_exp2f(tq.z * LOG2E)) + 0x8000u;
      unsigned u3 = __float_as_uint(__builtin_amdgcn_exp2f(tq.w * LOG2E)) + 0x8000u;
      Mp[2 * q + 0] = __builtin_amdgcn_perm(u1, u0, 0x07060302u);  // [lo=bf16(x), hi=bf16(y)]
      Mp[2 * q + 1] = __builtin_amdgcn_perm(u3, u2, 0x07060302u);
    }
  }
#else
  float Mf[64];
  {
    const float4* trow = (const float4*)(trans + lane * N);
#pragma unroll
    for (int q = 0; q < 16; ++q) {
      float4 tq = trow[q];
      Mf[4 * q + 0] = __builtin_amdgcn_exp2f(tq.x * LOG2E);
      Mf[4 * q + 1] = __builtin_amdgcn_exp2f(tq.y * LOG2E);
      Mf[4 * q + 2] = __builtin_amdgcn_exp2f(tq.z * LOG2E);
      Mf[4 * q + 3] = __builtin_amdgcn_exp2f(tq.w * LOG2E);
    }
  }
#endif

  const int len = lengths[b];

  // Step t=0 closed form (exp(-10000+x)==0 in fp32): u = exp(h0 + trans[:,START])
  float u = __builtin_amdgcn_exp2f((hb[lane] + trans[lane * N + (N - 2)]) * LOG2E);
  int kprev = __builtin_amdgcn_readfirstlane(__builtin_amdgcn_frexp_expf(u));
  int K = 0;

  auto step = [&](float e_raw) {
    float E = __builtin_amdgcn_exp2f(e_raw * LOG2E);  // off the serial chain
    float acc0 = 0, acc1 = 0, acc2 = 0, acc3 = 0,
          acc4 = 0, acc5 = 0, acc6 = 0, acc7 = 0;
#if HAVE_BF16_DOT2
    unsigned wr = __float_as_uint(u) + 0x8000u;                       // round
    unsigned wo = __builtin_amdgcn_mov_dpp(wr, 0xB1, 0xF, 0xF, true); // xor 1
    unsigned pair = __builtin_amdgcn_perm(wo, wr, 0x07060302u);       // even lanes: (w2a, w2a+1)
    float accs[8] = {0, 0, 0, 0, 0, 0, 0, 0};
#pragma unroll
    for (int a = 0; a < 32; ++a) {
      unsigned wp = (unsigned)__builtin_amdgcn_readlane((int)pair, 2 * a);
      accs[a & 7] = __builtin_amdgcn_fdot2_f32_bf16(
          __builtin_bit_cast(bf16x2, Mp[a]), __builtin_bit_cast(bf16x2, wp),
          accs[a & 7], false);
    }
    acc0 = accs[0]; acc1 = accs[1]; acc2 = accs[2]; acc3 = accs[3];
    acc4 = accs[4]; acc5 = accs[5]; acc6 = accs[6]; acc7 = accs[7];
#else
#pragma unroll
    for (int j = 0; j < 64; j += 8) {
      acc0 = fmaf(Mf[j + 0], bcastf(u, j + 0), acc0);
      acc1 = fmaf(Mf[j + 1], bcastf(u, j + 1), acc1);
      acc2 = fmaf(Mf[j + 2], bcastf(u, j + 2), acc2);
      acc3 = fmaf(Mf[j + 3], bcastf(u, j + 3), acc3);
      acc4 = fmaf(Mf[j + 4], bcastf(u, j + 4), acc4);
      acc5 = fmaf(Mf[j + 5], bcastf(u, j + 5), acc5);
      acc6 = fmaf(Mf[j + 6], bcastf(u, j + 6), acc6);
      acc7 = fmaf(Mf[j + 7], bcastf(u, j + 7), acc7);
    }
#endif
    float s = ((acc0 + acc1) + (acc2 + acc3)) + ((acc4 + acc5) + (acc6 + acc7));
    u = ldexpf(s * E, -kprev);   // exact pow2 rescale, k lagged one step
    K += kprev;
    kprev = __builtin_amdgcn_readfirstlane(__builtin_amdgcn_frexp_expf(s));
  };

  // Software-pipelined emissions (raw), 8 deep.
  float eb[8];
#pragma unroll
  for (int uu = 0; uu < 8; ++uu) {
    int t0 = 1 + uu;
    int tc = t0 < T ? t0 : T - 1;
    eb[uu] = hb[(size_t)tc * N + lane];
  }

  int t = 1;
  for (; t + 8 <= len; t += 8) {
#pragma unroll
    for (int uu = 0; uu < 8; ++uu) {
      step(eb[uu]);
      int tn = t + uu + 8;
      int tc = tn < T ? tn : T - 1;  // in-bounds; value unused past len
      eb[uu] = hb[(size_t)tc * N + lane];
    }
  }
  for (; t < len; ++t) {  // <=7 tail steps
    step(hb[(size_t)t * N + lane]);
  }

  // score2[i] = log2(u) + K; terminal END transition; wave-wide logsumexp.
  float fin2 = __builtin_amdgcn_logf(u) + (float)K +
               trans[(N - 1) * N + lane] * LOG2E;
  float m2 = fin2;
#pragma unroll
  for (int off = 32; off >= 1; off >>= 1)
    m2 = fmaxf(m2, __shfl_xor(m2, off, 64));
  float z = __builtin_amdgcn_exp2f(fin2 - m2);
#pragma unroll
  for (int off = 32; off >= 1; off >>= 1)
    z += __shfl_xor(z, off, 64);
  if (lane == 0) out[b] = LN2 * (m2 + __builtin_amdgcn_logf(z));
}

extern "C" void kernel_launch(void* const* d_in, const int* in_sizes, int n_in,
                              void* d_out, int out_size, void* d_ws, size_t ws_size,
                              hipStream_t stream) {
  const float* h = (const float*)d_in[0];
  const float* trans = (const float*)d_in[1];
  const int* lengths = (const int*)d_in[2];
  float* out = (float*)d_out;
  const int B = in_sizes[2];
  const int N = 64;
  const int T = in_sizes[0] / (B * N);
  crf_fwd_33852932227637<<<B, 64, 0, stream>>>(h, trans, lengths, out, T);
}